// Round 11
// baseline (300.403 us; speedup 1.0000x reference)
//
#include <hip/hip_runtime.h>
#include <math.h>

#define N_NODES 16000
#define F_IN    16
#define HID     256
#define OUTD    128
#define KNN     8
#define LAYERS  3
#define NEDGE   (N_NODES * KNN)

#define NPAD    16384
#define PARTS   4
#define PART_SZ (NPAD / PARTS)   // 4096
#define HALF_SZ 2048             // min-pass scans only first half of each part
#define SEGS    32               // segs per part (8 queries/thread)
#define NMIN    (PARTS * SEGS)   // 128 per-seg minima per query
#define CAPP    32               // collected-candidate cap per (query, part)

typedef __attribute__((ext_vector_type(8))) short  s8v;   // 8 bf16
typedef __attribute__((ext_vector_type(4))) float  f4v;

__device__ __forceinline__ unsigned short f2bf(float x) {
    unsigned u = __float_as_uint(x);
    unsigned r = u + 0x7fffu + ((u >> 16) & 1u);   // RNE
    return (unsigned short)(r >> 16);
}
__device__ __forceinline__ float bf2f(unsigned short b) {
    return __uint_as_float(((unsigned)b) << 16);
}

// ---------------------------------------------------------------------------
// cand[i] = (-2x, -2y, -2z, |c|^2); INF-padded. Shifted distance
// d' = fma(qx,-2x, fma(qy,-2y, fma(qz,-2z, |c|^2))) is per-query monotone.
// Also zeroes indeg+cursor (8000 int4) and gsumP (4096 int4).
// ---------------------------------------------------------------------------
__global__ __launch_bounds__(256) void prep_kernel(const float* __restrict__ coords,
                                                   float4* __restrict__ cand,
                                                   int4* __restrict__ zeroA,
                                                   int4* __restrict__ zeroB) {
    int i = blockIdx.x * 256 + threadIdx.x;
    int4 z4 = {0, 0, 0, 0};
    if (i < 8000) zeroA[i] = z4;
    if (i < 4096) zeroB[i] = z4;
    if (i >= NPAD) return;
    if (i < N_NODES) {
        float x = coords[3 * i], y = coords[3 * i + 1], z2 = coords[3 * i + 2];
        cand[i] = make_float4(-2.f * x, -2.f * y, -2.f * z2, x * x + y * y + z2 * z2);
    } else {
        cand[i] = make_float4(0.f, 0.f, 0.f, INFINITY);
    }
}

#define DIST(qx, qy, qz, c) fmaf(qx, c.x, fmaf(qy, c.y, fmaf(qz, c.z, c.w)))

// ---------------------------------------------------------------------------
// Phase 1: per (query, part, seg) minimum over the FIRST HALF of each part
// (8192-candidate subset). 8 queries/thread, branchless, direct L2 reads.
// ---------------------------------------------------------------------------
__global__ __launch_bounds__(256) void knn_min_kernel(const float* __restrict__ coords,
                                                      const float4* __restrict__ cand,
                                                      float* __restrict__ minv) {
    int tid  = threadIdx.x;
    int seg  = tid & 31;
    int qg   = tid >> 5;
    int qbase = blockIdx.x * 64;
    int part = blockIdx.y;

    float qx[8], qy[8], qz[8], m[8];
#pragma unroll
    for (int i = 0; i < 8; ++i) {
        int q = qbase + i * 8 + qg;
        qx[i] = coords[q * 3]; qy[i] = coords[q * 3 + 1]; qz[i] = coords[q * 3 + 2];
        m[i] = INFINITY;
    }

    int pbase = part * PART_SZ;
#pragma unroll 2
    for (int c0 = 0; c0 < HALF_SZ; c0 += 128) {
        float4 v0 = cand[pbase + c0 + seg];
        float4 v1 = cand[pbase + c0 + seg + 32];
        float4 v2 = cand[pbase + c0 + seg + 64];
        float4 v3 = cand[pbase + c0 + seg + 96];
#pragma unroll
        for (int i = 0; i < 8; ++i) {
            float d0 = DIST(qx[i], qy[i], qz[i], v0);
            float d1 = DIST(qx[i], qy[i], qz[i], v1);
            float d2 = DIST(qx[i], qy[i], qz[i], v2);
            float d3 = DIST(qx[i], qy[i], qz[i], v3);
            m[i] = fminf(m[i], fminf(fminf(d0, d1), fminf(d2, d3)));
        }
    }
#pragma unroll
    for (int i = 0; i < 8; ++i) {
        int q = qbase + i * 8 + qg;
        minv[(q * PARTS + part) * SEGS + seg] = m[i];
    }
}

// ---------------------------------------------------------------------------
// Phase 2: tau[q] = 9th smallest of 16 merged-list minima (each list = 8
// consecutive segs -> minima of 16 disjoint sets of real candidates -> each
// is a distinct candidate's distance -> 9th smallest >= true d9: valid bound.
// ---------------------------------------------------------------------------
__global__ __launch_bounds__(256) void tau_kernel(const float* __restrict__ minv,
                                                  float* __restrict__ tau) {
    int q = blockIdx.x * 256 + threadIdx.x;
    if (q >= N_NODES) return;
    float b[9];
#pragma unroll
    for (int p = 0; p < 9; ++p) b[p] = INFINITY;
    const float4* mv = (const float4*)(minv + (size_t)q * NMIN);
#pragma unroll
    for (int c = 0; c < 16; ++c) {
        float4 a0 = mv[c * 2], a1 = mv[c * 2 + 1];
        float v = fminf(fminf(fminf(a0.x, a0.y), fminf(a0.z, a0.w)),
                        fminf(fminf(a1.x, a1.y), fminf(a1.z, a1.w)));
#pragma unroll
        for (int p = 8; p >= 1; --p) {
            bool  up = v < b[p - 1];
            b[p] = up ? b[p - 1] : (v < b[p] ? v : b[p]);
        }
        if (v < b[0]) b[0] = v;
    }
    tau[q] = b[8];
}

// ---------------------------------------------------------------------------
// Phase 3: collect candidates with d <= tau[q] over the FULL set. min4-gate;
// direct L2 reads; block-local LDS counters. Identical fma as phase 1 ->
// bit-identical d on the subset -> bound exact; INF pad never collected.
// ---------------------------------------------------------------------------
__global__ __launch_bounds__(256) void knn_collect_kernel(const float* __restrict__ coords,
                                                          const float4* __restrict__ cand,
                                                          const float* __restrict__ tau,
                                                          int* __restrict__ cnt,
                                                          float2* __restrict__ cl) {
    __shared__ int scnt[64];
    int tid  = threadIdx.x;
    int seg  = tid & 31;
    int qg   = tid >> 5;
    int qbase = blockIdx.x * 64;
    int part  = blockIdx.y;

    float qx[8], qy[8], qz[8], tt[8];
#pragma unroll
    for (int i = 0; i < 8; ++i) {
        int q = qbase + i * 8 + qg;
        qx[i] = coords[q * 3]; qy[i] = coords[q * 3 + 1]; qz[i] = coords[q * 3 + 2];
        tt[i] = tau[q];
    }
    if (tid < 64) scnt[tid] = 0;
    __syncthreads();

    int pbase = part * PART_SZ;
    for (int c0 = 0; c0 < PART_SZ; c0 += 128) {
        float4 v0 = cand[pbase + c0 + seg];
        float4 v1 = cand[pbase + c0 + seg + 32];
        float4 v2 = cand[pbase + c0 + seg + 64];
        float4 v3 = cand[pbase + c0 + seg + 96];
        int jb = pbase + c0 + seg;
#pragma unroll
        for (int i = 0; i < 8; ++i) {
            float d0 = DIST(qx[i], qy[i], qz[i], v0);
            float d1 = DIST(qx[i], qy[i], qz[i], v1);
            float d2 = DIST(qx[i], qy[i], qz[i], v2);
            float d3 = DIST(qx[i], qy[i], qz[i], v3);
            float m4 = fminf(fminf(d0, d1), fminf(d2, d3));
            if (m4 <= tt[i]) {
                int qi = qbase + i * 8 + qg;
                int cb = (int)(((size_t)qi * PARTS + part) * CAPP);
                if (d0 <= tt[i]) {
                    int pos = atomicAdd(&scnt[i * 8 + qg], 1);
                    if (pos < CAPP) cl[cb + pos] = make_float2(d0, __int_as_float(jb));
                }
                if (d1 <= tt[i]) {
                    int pos = atomicAdd(&scnt[i * 8 + qg], 1);
                    if (pos < CAPP) cl[cb + pos] = make_float2(d1, __int_as_float(jb + 32));
                }
                if (d2 <= tt[i]) {
                    int pos = atomicAdd(&scnt[i * 8 + qg], 1);
                    if (pos < CAPP) cl[cb + pos] = make_float2(d2, __int_as_float(jb + 64));
                }
                if (d3 <= tt[i]) {
                    int pos = atomicAdd(&scnt[i * 8 + qg], 1);
                    if (pos < CAPP) cl[cb + pos] = make_float2(d3, __int_as_float(jb + 96));
                }
            }
        }
    }
    __syncthreads();
    if (tid < 64) cnt[(size_t)(qbase + tid) * PARTS + part] = scnt[tid];
}

// ---------------------------------------------------------------------------
// Phase 4: exact lexicographic (d, idx) top-9 over the 4 part segments.
// Also counts indegree (fused). Fallback: exact full rescan on overflow.
// ---------------------------------------------------------------------------
#define INS9L(bd, bi, d, j)                                                   \
    {                                                                         \
        _Pragma("unroll")                                                     \
        for (int p = 8; p >= 1; --p) {                                        \
            bool up = (d) < bd[p-1] || ((d) == bd[p-1] && (j) < bi[p-1]);     \
            bool in = (d) < bd[p]   || ((d) == bd[p]   && (j) < bi[p]);       \
            float nd = up ? bd[p-1] : (in ? (d) : bd[p]);                     \
            int   ni = up ? bi[p-1] : (in ? (j) : bi[p]);                     \
            bd[p] = nd; bi[p] = ni;                                           \
        }                                                                     \
        if ((d) < bd[0] || ((d) == bd[0] && (j) < bi[0])) {                   \
            bd[0] = (d); bi[0] = (j);                                         \
        }                                                                     \
    }

__global__ __launch_bounds__(256) void knn_select_kernel(const float* __restrict__ coords,
                                                         const float4* __restrict__ cand,
                                                         const float2* __restrict__ cl,
                                                         const int* __restrict__ cnt,
                                                         int* __restrict__ nbr,
                                                         int* __restrict__ indeg) {
    int q = blockIdx.x * 256 + threadIdx.x;
    if (q >= N_NODES) return;
    float bd[9]; int bi[9];
#pragma unroll
    for (int p = 0; p < 9; ++p) { bd[p] = INFINITY; bi[p] = 0x7fffffff; }
    int n0 = cnt[(size_t)q * PARTS + 0];
    int n1 = cnt[(size_t)q * PARTS + 1];
    int n2 = cnt[(size_t)q * PARTS + 2];
    int n3 = cnt[(size_t)q * PARTS + 3];
    if (n0 <= CAPP && n1 <= CAPP && n2 <= CAPP && n3 <= CAPP) {
#pragma unroll
        for (int p = 0; p < PARTS; ++p) {
            int n = (p == 0) ? n0 : (p == 1) ? n1 : (p == 2) ? n2 : n3;
            const float2* segp = cl + ((size_t)q * PARTS + p) * CAPP;
            for (int i = 0; i < n; ++i) {
                float2 e = segp[i];
                float d = e.x; int j = __float_as_int(e.y);
                INS9L(bd, bi, d, j);
            }
        }
    } else {
        float qx = coords[q*3], qy = coords[q*3+1], qz = coords[q*3+2];
        for (int j = 0; j < NPAD; ++j) {
            float4 c = cand[j];
            float d = DIST(qx, qy, qz, c);
            if (d < bd[8] || (d == bd[8] && j < bi[8])) INS9L(bd, bi, d, j);
        }
    }
#pragma unroll
    for (int p = 1; p < 9; ++p) {
        nbr[q * 8 + p - 1] = bi[p];
        atomicAdd(&indeg[bi[p]], 1);
    }
}

// ---------------------------------------------------------------------------
// CSR: exclusive scan (+norm) over indegree, then fill.
// ---------------------------------------------------------------------------
__global__ __launch_bounds__(1024) void scan_kernel(const int* __restrict__ indeg,
                                                    int* __restrict__ offs,
                                                    float* __restrict__ norm) {
    __shared__ int ssum[1024];
    int t = threadIdx.x;
    const int CH = 16;
    int base = t * CH;
    int s = 0;
    for (int c = 0; c < CH; ++c) {
        int idx = base + c;
        if (idx < N_NODES) s += indeg[idx];
    }
    ssum[t] = s;
    __syncthreads();
    for (int d = 1; d < 1024; d <<= 1) {
        int v = (t >= d) ? ssum[t - d] : 0;
        __syncthreads();
        ssum[t] += v;
        __syncthreads();
    }
    int run = ssum[t] - s;
    for (int c = 0; c < CH; ++c) {
        int idx = base + c;
        if (idx < N_NODES) {
            int dg = indeg[idx];
            offs[idx] = run;
            run += dg;
            norm[idx] = rsqrtf((float)(1 + dg));
        }
    }
    if (t == 1023) offs[N_NODES] = ssum[1023];
}

__global__ void fill_kernel(const int* __restrict__ nbr, const int* __restrict__ offs,
                            int* __restrict__ cursor, int* __restrict__ adj) {
    int e = blockIdx.x * blockDim.x + threadIdx.x;
    if (e < NEDGE) {
        int d   = nbr[e];
        int src = e >> 3;
        int pos = atomicAdd(&cursor[d], 1);
        adj[offs[d] + pos] = src;
    }
}

// ---------------------------------------------------------------------------
// Encoder GEMM (f32 in, bf16 out, K=16): h = bf16(x @ We + be).
// blockIdx.y==4 slice performs the W transpose+split (barrier-free branch).
// ---------------------------------------------------------------------------
__global__ __launch_bounds__(256) void gemm_kernel(const float* __restrict__ A,
                                                   const float* __restrict__ B,
                                                   unsigned short* __restrict__ C,
                                                   int K,
                                                   const float* __restrict__ bias,
                                                   const float* __restrict__ Wg,
                                                   unsigned short* __restrict__ WThi,
                                                   unsigned short* __restrict__ WTlo) {
    if (blockIdx.y == 4) {
        for (int idx = blockIdx.x * 256 + threadIdx.x; idx < LAYERS * 65536;
             idx += 64000) {
            int l = idx >> 16;
            int r = idx & 65535;
            int k = r >> 8, j = r & 255;
            float xv = Wg[idx];
            unsigned short hb = f2bf(xv);
            size_t o = (size_t)l * 65536 + j * 256 + k;
            WThi[o] = hb;
            WTlo[o] = f2bf(xv - bf2f(hb));
        }
        return;
    }
    __shared__ float As[16][68];
    __shared__ float Bs[16][64];
    int tid = threadIdx.x;
    int rowBase = blockIdx.x * 64;
    int colBase = blockIdx.y * 64;
    int rg = tid >> 4;
    int cg = tid & 15;

    int ar = tid >> 2;
    int ac = (tid & 3) * 4;
    int bk = tid >> 4;
    int bn = (tid & 15) * 4;

    float4 acc0 = {0,0,0,0}, acc1 = {0,0,0,0}, acc2 = {0,0,0,0}, acc3 = {0,0,0,0};

    for (int kb = 0; kb < K; kb += 16) {
        float4 av = *(const float4*)(A + (size_t)(rowBase + ar) * K + kb + ac);
        float4 bv = *(const float4*)(B + (size_t)(kb + bk) * HID + colBase + bn);
        __syncthreads();
        As[ac + 0][ar] = av.x; As[ac + 1][ar] = av.y;
        As[ac + 2][ar] = av.z; As[ac + 3][ar] = av.w;
        *(float4*)&Bs[bk][bn] = bv;
        __syncthreads();
#pragma unroll
        for (int k = 0; k < 16; ++k) {
            float4 a = *(const float4*)&As[k][rg * 4];
            float4 b = *(const float4*)&Bs[k][cg * 4];
            acc0.x = fmaf(a.x, b.x, acc0.x); acc0.y = fmaf(a.x, b.y, acc0.y);
            acc0.z = fmaf(a.x, b.z, acc0.z); acc0.w = fmaf(a.x, b.w, acc0.w);
            acc1.x = fmaf(a.y, b.x, acc1.x); acc1.y = fmaf(a.y, b.y, acc1.y);
            acc1.z = fmaf(a.y, b.z, acc1.z); acc1.w = fmaf(a.y, b.w, acc1.w);
            acc2.x = fmaf(a.z, b.x, acc2.x); acc2.y = fmaf(a.z, b.y, acc2.y);
            acc2.z = fmaf(a.z, b.z, acc2.z); acc2.w = fmaf(a.z, b.w, acc2.w);
            acc3.x = fmaf(a.w, b.x, acc3.x); acc3.y = fmaf(a.w, b.y, acc3.y);
            acc3.z = fmaf(a.w, b.z, acc3.z); acc3.w = fmaf(a.w, b.w, acc3.w);
        }
        __syncthreads();
    }

    int row = rowBase + rg * 4;
    int col = colBase + cg * 4;
    float4 bb = *(const float4*)(bias + col);

    ushort4 o;
    o.x = f2bf(acc0.x + bb.x); o.y = f2bf(acc0.y + bb.y);
    o.z = f2bf(acc0.z + bb.z); o.w = f2bf(acc0.w + bb.w);
    *(ushort4*)(C + (size_t)(row + 0) * HID + col) = o;
    o.x = f2bf(acc1.x + bb.x); o.y = f2bf(acc1.y + bb.y);
    o.z = f2bf(acc1.z + bb.z); o.w = f2bf(acc1.w + bb.w);
    *(ushort4*)(C + (size_t)(row + 1) * HID + col) = o;
    o.x = f2bf(acc2.x + bb.x); o.y = f2bf(acc2.y + bb.y);
    o.z = f2bf(acc2.z + bb.z); o.w = f2bf(acc2.w + bb.w);
    *(ushort4*)(C + (size_t)(row + 2) * HID + col) = o;
    o.x = f2bf(acc3.x + bb.x); o.y = f2bf(acc3.y + bb.y);
    o.z = f2bf(acc3.z + bb.z); o.w = f2bf(acc3.w + bb.w);
    *(ushort4*)(C + (size_t)(row + 3) * HID + col) = o;
}

// ---------------------------------------------------------------------------
// MFMA GEMM, A pure bf16: u16 = bf16((h @ W) * norm[row]).
// A exact bf16 -> only 2 MFMAs per tile: A*Bhi + A*Blo.  64x64, grid (250,4).
// ---------------------------------------------------------------------------
__global__ __launch_bounds__(256) void mfma_gemm_kernel(const unsigned short* __restrict__ A,
                                                        const unsigned short* __restrict__ WThi,
                                                        const unsigned short* __restrict__ WTlo,
                                                        unsigned short* __restrict__ C,
                                                        const float* __restrict__ rowscale) {
    __shared__ unsigned short Ah[64][40];
    __shared__ unsigned short Bh[64][40], Bl[64][40];
    int tid = threadIdx.x;
    int rowBase = blockIdx.x * 64;
    int colBase = blockIdx.y * 64;
    int wave = tid >> 6;
    int lane = tid & 63;
    int fr = lane & 15;
    int fg = lane >> 4;

    int asr = tid >> 2;          // 0..63 : row (A) / col (WT row)
    int ask = (tid & 3) * 8;     // k-offset, 8 ushorts = 16 B

    f4v acc[4];
#pragma unroll
    for (int c = 0; c < 4; ++c) acc[c] = (f4v){0.f, 0.f, 0.f, 0.f};

    for (int kb = 0; kb < HID; kb += 32) {
        uint4 av = *(const uint4*)(A    + (size_t)(rowBase + asr) * HID + kb + ask);
        uint4 bh = *(const uint4*)(WThi + (size_t)(colBase + asr) * HID + kb + ask);
        uint4 bl = *(const uint4*)(WTlo + (size_t)(colBase + asr) * HID + kb + ask);
        __syncthreads();
        *(uint4*)&Ah[asr][ask] = av;
        *(uint4*)&Bh[asr][ask] = bh;
        *(uint4*)&Bl[asr][ask] = bl;
        __syncthreads();

        s8v af = *(s8v*)&Ah[wave * 16 + fr][fg * 8];
#pragma unroll
        for (int c = 0; c < 4; ++c) {
            s8v bfh = *(s8v*)&Bh[c * 16 + fr][fg * 8];
            s8v bfl = *(s8v*)&Bl[c * 16 + fr][fg * 8];
            acc[c] = __builtin_amdgcn_mfma_f32_16x16x32_bf16(af, bfh, acc[c], 0, 0, 0);
            acc[c] = __builtin_amdgcn_mfma_f32_16x16x32_bf16(af, bfl, acc[c], 0, 0, 0);
        }
    }

    float sc[4];
#pragma unroll
    for (int r = 0; r < 4; ++r) sc[r] = rowscale[rowBase + wave * 16 + fg * 4 + r];
#pragma unroll
    for (int c = 0; c < 4; ++c) {
        int col = colBase + c * 16 + fr;
#pragma unroll
        for (int r = 0; r < 4; ++r) {
            int row = rowBase + wave * 16 + fg * 4 + r;
            C[(size_t)row * HID + col] = f2bf(acc[c][r] * sc[r]);
        }
    }
}

// ---------------------------------------------------------------------------
// Aggregation: h[j] = relu(norm[j]*(u[j]+sum_in u)+b), bf16 in/out.
// If gsumP != null (last layer): accumulate block partial feature sums
// (f32, pre-rounding) into gsumP[blockIdx&63][256] -> replaces pool kernel.
// ---------------------------------------------------------------------------
__global__ __launch_bounds__(256) void agg_kernel(const unsigned short* __restrict__ u,
                                                  const float* __restrict__ norm,
                                                  const float* __restrict__ bias,
                                                  const int* __restrict__ offs,
                                                  const int* __restrict__ adj,
                                                  unsigned short* __restrict__ hout,
                                                  float* __restrict__ gsumP) {
    __shared__ float sacc[256];
    int tid  = threadIdx.x;
    int node = blockIdx.x * 4 + (tid >> 6);
    int lane = tid & 63;
    const ushort4* up = (const ushort4*)u;
    ushort4 sv = up[(size_t)node * 64 + lane];
    float ax = bf2f(sv.x), ay = bf2f(sv.y), az = bf2f(sv.z), aw = bf2f(sv.w);
    int e0 = offs[node], e1 = offs[node + 1];
    for (int e = e0; e < e1; ++e) {
        int s = adj[e];
        ushort4 v = up[(size_t)s * 64 + lane];
        ax += bf2f(v.x); ay += bf2f(v.y); az += bf2f(v.z); aw += bf2f(v.w);
    }
    float nm = norm[node];
    float4 bb = ((const float4*)bias)[lane];
    float4 r;
    r.x = fmaxf(fmaf(nm, ax, bb.x), 0.0f);
    r.y = fmaxf(fmaf(nm, ay, bb.y), 0.0f);
    r.z = fmaxf(fmaf(nm, az, bb.z), 0.0f);
    r.w = fmaxf(fmaf(nm, aw, bb.w), 0.0f);
    ushort4 o;
    o.x = f2bf(r.x); o.y = f2bf(r.y); o.z = f2bf(r.z); o.w = f2bf(r.w);
    ((ushort4*)hout)[(size_t)node * 64 + lane] = o;

    if (gsumP) {
        sacc[tid] = 0.0f;
        __syncthreads();
        atomicAdd(&sacc[lane * 4 + 0], r.x);
        atomicAdd(&sacc[lane * 4 + 1], r.y);
        atomicAdd(&sacc[lane * 4 + 2], r.z);
        atomicAdd(&sacc[lane * 4 + 3], r.w);
        __syncthreads();
        atomicAdd(&gsumP[(blockIdx.x & 63) * 256 + tid], sacc[tid]);
    }
}

// ---------------------------------------------------------------------------
// Head: reduce 64 pool partials, then 2-layer MLP (f32).
// ---------------------------------------------------------------------------
__global__ __launch_bounds__(128) void head_kernel(const float* __restrict__ gsumP,
                                                   const float* __restrict__ Wp1,
                                                   const float* __restrict__ bp1,
                                                   const float* __restrict__ Wp2,
                                                   const float* __restrict__ bp2,
                                                   float* __restrict__ out) {
    __shared__ float gl[256];
    __shared__ float hid[128];
    int t = threadIdx.x;
    const float inv = 1.0f / 16000.0f;
    float s0 = 0.f, s1 = 0.f;
    for (int p = 0; p < 64; ++p) {
        s0 += gsumP[p * 256 + t];
        s1 += gsumP[p * 256 + t + 128];
    }
    gl[t]       = s0 * inv;
    gl[t + 128] = s1 * inv;
    __syncthreads();
    float a = bp1[t];
    for (int k = 0; k < 256; ++k) a = fmaf(gl[k], Wp1[k * 128 + t], a);
    hid[t] = fmaxf(a, 0.0f);
    __syncthreads();
    float o = bp2[t];
    for (int k = 0; k < 128; ++k) o = fmaf(hid[k], Wp2[k * 128 + t], o);
    out[t] = o;
}

// ---------------------------------------------------------------------------
extern "C" void kernel_launch(void* const* d_in, const int* in_sizes, int n_in,
                              void* d_out, int out_size, void* d_ws, size_t ws_size,
                              hipStream_t stream) {
    const float* x      = (const float*)d_in[0];
    const float* coords = (const float*)d_in[1];
    const float* We     = (const float*)d_in[2];
    const float* be     = (const float*)d_in[3];
    const float* gnn_W  = (const float*)d_in[4];
    const float* gnn_b  = (const float*)d_in[5];
    const float* Wp1    = (const float*)d_in[6];
    const float* bp1    = (const float*)d_in[7];
    const float* Wp2    = (const float*)d_in[8];
    const float* bp2    = (const float*)d_in[9];
    float* out = (float*)d_out;

    char* ws = (char*)d_ws;
    // ws layout, high-water 34,311,424 B (proven).
    // NOTE: never end a comment with a backslash (line continuation!).
    unsigned short* h = (unsigned short*)(ws + 0);  // 8,192,000 B bf16 (region 16.38 MB)
    char*  ureg  = ws + 16384000;             // 16,384,000 B multi-use region
    int*   nbr   = (int*)  (ws + 32768000);   // 512,000 B
    int*   adj   = (int*)  (ws + 33280000);   // 512,000 B
    int*   indeg = (int*)  (ws + 33792000);   // 64,000 B (zeroA start)
    int*   cursor= (int*)  (ws + 33856000);   // 64,000 B (zeroA end: 128,000 B)
    int*   offs  = (int*)  (ws + 33921024);   // 64,004 B
    float* norm  = (float*)(ws + 33985152);   // 64,000 B
    float4* cand = (float4*)(ws + 34049280);  // 262,144 B

    // ureg during kNN: minv, tau, cnt.  During GNN: u16, WThi, WTlo, gsumP.
    unsigned short* u16 = (unsigned short*)ureg;              // 8,192,000 B
    float*  minv = (float*)ureg;                              // 8,192,000 B
    float*  tau  = (float*)(ureg + 8192000);                  // 64,000 B
    int*    cnt  = (int*)  (ureg + 8256000);                  // 256,000 B
    unsigned short* WThi = (unsigned short*)(ureg + 8512000); // 393,216 B
    unsigned short* WTlo = (unsigned short*)(ureg + 8905216); // 393,216 B
    float*  gsumP = (float*)(ureg + 9298432);                 // 65,536 B (zeroB)
    float2* cl   = (float2*)(ws + 0);                         // 16,384,000 B (kNN phase)

    prep_kernel<<<NPAD / 256, 256, 0, stream>>>(coords, cand, (int4*)indeg, (int4*)gsumP);
    knn_min_kernel<<<dim3(N_NODES / 64, PARTS), 256, 0, stream>>>(coords, cand, minv);
    tau_kernel<<<(N_NODES + 255) / 256, 256, 0, stream>>>(minv, tau);
    knn_collect_kernel<<<dim3(N_NODES / 64, PARTS), 256, 0, stream>>>(coords, cand, tau, cnt, cl);
    knn_select_kernel<<<(N_NODES + 255) / 256, 256, 0, stream>>>(coords, cand, cl, cnt, nbr, indeg);

    scan_kernel<<<1, 1024, 0, stream>>>(indeg, offs, norm);
    fill_kernel<<<(NEDGE + 255) / 256, 256, 0, stream>>>(nbr, offs, cursor, adj);

    // encoder GEMM (y=0..3) + wsplit slice (y=4) in one dispatch
    gemm_kernel<<<dim3(N_NODES / 64, 5), 256, 0, stream>>>(x, We, h, F_IN, be,
                                                           gnn_W, WThi, WTlo);
    for (int l = 0; l < LAYERS; ++l) {
        mfma_gemm_kernel<<<dim3(N_NODES / 64, 4), 256, 0, stream>>>(
            h, WThi + (size_t)l * 65536, WTlo + (size_t)l * 65536, u16, norm);
        agg_kernel<<<N_NODES / 4, 256, 0, stream>>>(u16, norm, gnn_b + (size_t)l * HID,
                                                    offs, adj, h,
                                                    (l == LAYERS - 1) ? gsumP : nullptr);
    }
    head_kernel<<<1, 128, 0, stream>>>(gsumP, Wp1, bp1, Wp2, bp2, out);
}

// Round 12
// 275.678 us; speedup vs baseline: 1.0897x; 1.0897x over previous
//
#include <hip/hip_runtime.h>
#include <math.h>

#define N_NODES 16000
#define F_IN    16
#define HID     256
#define OUTD    128
#define KNN     8
#define LAYERS  3
#define NEDGE   (N_NODES * KNN)

#define NPAD    16384
#define PARTS   4
#define PART_SZ (NPAD / PARTS)   // 4096
#define SEGS    32               // segs per part (8 queries/thread)
#define NMIN    (PARTS * SEGS)   // 128 per-seg minima per query
#define CAPP    32               // collected-candidate cap per (query, part)

typedef __attribute__((ext_vector_type(8))) short  s8v;   // 8 bf16
typedef __attribute__((ext_vector_type(4))) float  f4v;

__device__ __forceinline__ unsigned short f2bf(float x) {
    unsigned u = __float_as_uint(x);
    unsigned r = u + 0x7fffu + ((u >> 16) & 1u);   // RNE
    return (unsigned short)(r >> 16);
}
__device__ __forceinline__ float bf2f(unsigned short b) {
    return __uint_as_float(((unsigned)b) << 16);
}

// ---------------------------------------------------------------------------
// cand[i] = (-2x, -2y, -2z, |c|^2); INF-padded. Shifted distance
// d' = fma(qx,-2x, fma(qy,-2y, fma(qz,-2z, |c|^2))) is per-query monotone.
// Also zeroes indeg+cursor (8000 int4) and gsumP (4096 int4).
// ---------------------------------------------------------------------------
__global__ __launch_bounds__(256) void prep_kernel(const float* __restrict__ coords,
                                                   float4* __restrict__ cand,
                                                   int4* __restrict__ zeroA,
                                                   int4* __restrict__ zeroB) {
    int i = blockIdx.x * 256 + threadIdx.x;
    int4 z4 = {0, 0, 0, 0};
    if (i < 8000) zeroA[i] = z4;
    if (i < 4096) zeroB[i] = z4;
    if (i >= NPAD) return;
    if (i < N_NODES) {
        float x = coords[3 * i], y = coords[3 * i + 1], z2 = coords[3 * i + 2];
        cand[i] = make_float4(-2.f * x, -2.f * y, -2.f * z2, x * x + y * y + z2 * z2);
    } else {
        cand[i] = make_float4(0.f, 0.f, 0.f, INFINITY);
    }
}

#define DIST(qx, qy, qz, c) fmaf(qx, c.x, fmaf(qy, c.y, fmaf(qz, c.z, c.w)))

// ---------------------------------------------------------------------------
// Phase 1: per (query, part, seg) minimum over the FULL part (tight tau is
// load-bearing: loose tau -> CAPP overflow -> serial fallback tail, round 11).
// 8 queries/thread, branchless, direct L2 reads (cand = 256 KB, L2-resident).
// ---------------------------------------------------------------------------
__global__ __launch_bounds__(256) void knn_min_kernel(const float* __restrict__ coords,
                                                      const float4* __restrict__ cand,
                                                      float* __restrict__ minv) {
    int tid  = threadIdx.x;
    int seg  = tid & 31;
    int qg   = tid >> 5;
    int qbase = blockIdx.x * 64;
    int part = blockIdx.y;

    float qx[8], qy[8], qz[8], m[8];
#pragma unroll
    for (int i = 0; i < 8; ++i) {
        int q = qbase + i * 8 + qg;
        qx[i] = coords[q * 3]; qy[i] = coords[q * 3 + 1]; qz[i] = coords[q * 3 + 2];
        m[i] = INFINITY;
    }

    int pbase = part * PART_SZ;
#pragma unroll 2
    for (int c0 = 0; c0 < PART_SZ; c0 += 128) {
        float4 v0 = cand[pbase + c0 + seg];
        float4 v1 = cand[pbase + c0 + seg + 32];
        float4 v2 = cand[pbase + c0 + seg + 64];
        float4 v3 = cand[pbase + c0 + seg + 96];
#pragma unroll
        for (int i = 0; i < 8; ++i) {
            float d0 = DIST(qx[i], qy[i], qz[i], v0);
            float d1 = DIST(qx[i], qy[i], qz[i], v1);
            float d2 = DIST(qx[i], qy[i], qz[i], v2);
            float d3 = DIST(qx[i], qy[i], qz[i], v3);
            m[i] = fminf(m[i], fminf(fminf(d0, d1), fminf(d2, d3)));
        }
    }
#pragma unroll
    for (int i = 0; i < 8; ++i) {
        int q = qbase + i * 8 + qg;
        minv[(q * PARTS + part) * SEGS + seg] = m[i];
    }
}

// ---------------------------------------------------------------------------
// Phase 2: tau[q] = 9th smallest of 16 merged-list minima (each list = 8
// consecutive segs -> 16 distinct candidates -> 9th smallest >= d9: valid).
// ---------------------------------------------------------------------------
__global__ __launch_bounds__(256) void tau_kernel(const float* __restrict__ minv,
                                                  float* __restrict__ tau) {
    int q = blockIdx.x * 256 + threadIdx.x;
    if (q >= N_NODES) return;
    float b[9];
#pragma unroll
    for (int p = 0; p < 9; ++p) b[p] = INFINITY;
    const float4* mv = (const float4*)(minv + (size_t)q * NMIN);
#pragma unroll
    for (int c = 0; c < 16; ++c) {
        float4 a0 = mv[c * 2], a1 = mv[c * 2 + 1];
        float v = fminf(fminf(fminf(a0.x, a0.y), fminf(a0.z, a0.w)),
                        fminf(fminf(a1.x, a1.y), fminf(a1.z, a1.w)));
#pragma unroll
        for (int p = 8; p >= 1; --p) {
            bool  up = v < b[p - 1];
            b[p] = up ? b[p - 1] : (v < b[p] ? v : b[p]);
        }
        if (v < b[0]) b[0] = v;
    }
    tau[q] = b[8];
}

// ---------------------------------------------------------------------------
// Phase 3: collect candidates with d <= tau[q]. min4-gate; direct L2 reads;
// block-local LDS counters. Identical fma as phase 1 -> bit-identical d.
// ---------------------------------------------------------------------------
__global__ __launch_bounds__(256) void knn_collect_kernel(const float* __restrict__ coords,
                                                          const float4* __restrict__ cand,
                                                          const float* __restrict__ tau,
                                                          int* __restrict__ cnt,
                                                          float2* __restrict__ cl) {
    __shared__ int scnt[64];
    int tid  = threadIdx.x;
    int seg  = tid & 31;
    int qg   = tid >> 5;
    int qbase = blockIdx.x * 64;
    int part  = blockIdx.y;

    float qx[8], qy[8], qz[8], tt[8];
#pragma unroll
    for (int i = 0; i < 8; ++i) {
        int q = qbase + i * 8 + qg;
        qx[i] = coords[q * 3]; qy[i] = coords[q * 3 + 1]; qz[i] = coords[q * 3 + 2];
        tt[i] = tau[q];
    }
    if (tid < 64) scnt[tid] = 0;
    __syncthreads();

    int pbase = part * PART_SZ;
    for (int c0 = 0; c0 < PART_SZ; c0 += 128) {
        float4 v0 = cand[pbase + c0 + seg];
        float4 v1 = cand[pbase + c0 + seg + 32];
        float4 v2 = cand[pbase + c0 + seg + 64];
        float4 v3 = cand[pbase + c0 + seg + 96];
        int jb = pbase + c0 + seg;
#pragma unroll
        for (int i = 0; i < 8; ++i) {
            float d0 = DIST(qx[i], qy[i], qz[i], v0);
            float d1 = DIST(qx[i], qy[i], qz[i], v1);
            float d2 = DIST(qx[i], qy[i], qz[i], v2);
            float d3 = DIST(qx[i], qy[i], qz[i], v3);
            float m4 = fminf(fminf(d0, d1), fminf(d2, d3));
            if (m4 <= tt[i]) {
                int qi = qbase + i * 8 + qg;
                int cb = (int)(((size_t)qi * PARTS + part) * CAPP);
                if (d0 <= tt[i]) {
                    int pos = atomicAdd(&scnt[i * 8 + qg], 1);
                    if (pos < CAPP) cl[cb + pos] = make_float2(d0, __int_as_float(jb));
                }
                if (d1 <= tt[i]) {
                    int pos = atomicAdd(&scnt[i * 8 + qg], 1);
                    if (pos < CAPP) cl[cb + pos] = make_float2(d1, __int_as_float(jb + 32));
                }
                if (d2 <= tt[i]) {
                    int pos = atomicAdd(&scnt[i * 8 + qg], 1);
                    if (pos < CAPP) cl[cb + pos] = make_float2(d2, __int_as_float(jb + 64));
                }
                if (d3 <= tt[i]) {
                    int pos = atomicAdd(&scnt[i * 8 + qg], 1);
                    if (pos < CAPP) cl[cb + pos] = make_float2(d3, __int_as_float(jb + 96));
                }
            }
        }
    }
    __syncthreads();
    if (tid < 64) cnt[(size_t)(qbase + tid) * PARTS + part] = scnt[tid];
}

// ---------------------------------------------------------------------------
// Phase 4: exact lexicographic (d, idx) top-9 over the 4 part segments.
// Also counts indegree (fused). Fallback exact rescan (~never fires with
// tight tau). 128-thread blocks for grid spread.
// ---------------------------------------------------------------------------
#define INS9L(bd, bi, d, j)                                                   \
    {                                                                         \
        _Pragma("unroll")                                                     \
        for (int p = 8; p >= 1; --p) {                                        \
            bool up = (d) < bd[p-1] || ((d) == bd[p-1] && (j) < bi[p-1]);     \
            bool in = (d) < bd[p]   || ((d) == bd[p]   && (j) < bi[p]);       \
            float nd = up ? bd[p-1] : (in ? (d) : bd[p]);                     \
            int   ni = up ? bi[p-1] : (in ? (j) : bi[p]);                     \
            bd[p] = nd; bi[p] = ni;                                           \
        }                                                                     \
        if ((d) < bd[0] || ((d) == bd[0] && (j) < bi[0])) {                   \
            bd[0] = (d); bi[0] = (j);                                         \
        }                                                                     \
    }

__global__ __launch_bounds__(128) void knn_select_kernel(const float* __restrict__ coords,
                                                         const float4* __restrict__ cand,
                                                         const float2* __restrict__ cl,
                                                         const int* __restrict__ cnt,
                                                         int* __restrict__ nbr,
                                                         int* __restrict__ indeg) {
    int q = blockIdx.x * 128 + threadIdx.x;
    if (q >= N_NODES) return;
    float bd[9]; int bi[9];
#pragma unroll
    for (int p = 0; p < 9; ++p) { bd[p] = INFINITY; bi[p] = 0x7fffffff; }
    int n0 = cnt[(size_t)q * PARTS + 0];
    int n1 = cnt[(size_t)q * PARTS + 1];
    int n2 = cnt[(size_t)q * PARTS + 2];
    int n3 = cnt[(size_t)q * PARTS + 3];
    if (n0 <= CAPP && n1 <= CAPP && n2 <= CAPP && n3 <= CAPP) {
#pragma unroll
        for (int p = 0; p < PARTS; ++p) {
            int n = (p == 0) ? n0 : (p == 1) ? n1 : (p == 2) ? n2 : n3;
            const float2* segp = cl + ((size_t)q * PARTS + p) * CAPP;
            for (int i = 0; i < n; ++i) {
                float2 e = segp[i];
                float d = e.x; int j = __float_as_int(e.y);
                INS9L(bd, bi, d, j);
            }
        }
    } else {
        float qx = coords[q*3], qy = coords[q*3+1], qz = coords[q*3+2];
        for (int j = 0; j < NPAD; ++j) {
            float4 c = cand[j];
            float d = DIST(qx, qy, qz, c);
            if (d < bd[8] || (d == bd[8] && j < bi[8])) INS9L(bd, bi, d, j);
        }
    }
#pragma unroll
    for (int p = 1; p < 9; ++p) {
        nbr[q * 8 + p - 1] = bi[p];
        atomicAdd(&indeg[bi[p]], 1);
    }
}

// ---------------------------------------------------------------------------
// CSR: exclusive scan (+norm) over indegree, then fill.
// ---------------------------------------------------------------------------
__global__ __launch_bounds__(1024) void scan_kernel(const int* __restrict__ indeg,
                                                    int* __restrict__ offs,
                                                    float* __restrict__ norm) {
    __shared__ int ssum[1024];
    int t = threadIdx.x;
    const int CH = 16;
    int base = t * CH;
    int s = 0;
    for (int c = 0; c < CH; ++c) {
        int idx = base + c;
        if (idx < N_NODES) s += indeg[idx];
    }
    ssum[t] = s;
    __syncthreads();
    for (int d = 1; d < 1024; d <<= 1) {
        int v = (t >= d) ? ssum[t - d] : 0;
        __syncthreads();
        ssum[t] += v;
        __syncthreads();
    }
    int run = ssum[t] - s;
    for (int c = 0; c < CH; ++c) {
        int idx = base + c;
        if (idx < N_NODES) {
            int dg = indeg[idx];
            offs[idx] = run;
            run += dg;
            norm[idx] = rsqrtf((float)(1 + dg));
        }
    }
    if (t == 1023) offs[N_NODES] = ssum[1023];
}

__global__ void fill_kernel(const int* __restrict__ nbr, const int* __restrict__ offs,
                            int* __restrict__ cursor, int* __restrict__ adj) {
    int e = blockIdx.x * blockDim.x + threadIdx.x;
    if (e < NEDGE) {
        int d   = nbr[e];
        int src = e >> 3;
        int pos = atomicAdd(&cursor[d], 1);
        adj[offs[d] + pos] = src;
    }
}

// ---------------------------------------------------------------------------
// Encoder GEMM (f32 in, bf16 out, K=16): h = bf16(x @ We + be).
// blockIdx.y==4 slice performs the W transpose+split (barrier-free branch).
// ---------------------------------------------------------------------------
__global__ __launch_bounds__(256) void gemm_kernel(const float* __restrict__ A,
                                                   const float* __restrict__ B,
                                                   unsigned short* __restrict__ C,
                                                   int K,
                                                   const float* __restrict__ bias,
                                                   const float* __restrict__ Wg,
                                                   unsigned short* __restrict__ WThi,
                                                   unsigned short* __restrict__ WTlo) {
    if (blockIdx.y == 4) {
        for (int idx = blockIdx.x * 256 + threadIdx.x; idx < LAYERS * 65536;
             idx += 64000) {
            int l = idx >> 16;
            int r = idx & 65535;
            int k = r >> 8, j = r & 255;
            float xv = Wg[idx];
            unsigned short hb = f2bf(xv);
            size_t o = (size_t)l * 65536 + j * 256 + k;
            WThi[o] = hb;
            WTlo[o] = f2bf(xv - bf2f(hb));
        }
        return;
    }
    __shared__ float As[16][68];
    __shared__ float Bs[16][64];
    int tid = threadIdx.x;
    int rowBase = blockIdx.x * 64;
    int colBase = blockIdx.y * 64;
    int rg = tid >> 4;
    int cg = tid & 15;

    int ar = tid >> 2;
    int ac = (tid & 3) * 4;
    int bk = tid >> 4;
    int bn = (tid & 15) * 4;

    float4 acc0 = {0,0,0,0}, acc1 = {0,0,0,0}, acc2 = {0,0,0,0}, acc3 = {0,0,0,0};

    for (int kb = 0; kb < K; kb += 16) {
        float4 av = *(const float4*)(A + (size_t)(rowBase + ar) * K + kb + ac);
        float4 bv = *(const float4*)(B + (size_t)(kb + bk) * HID + colBase + bn);
        __syncthreads();
        As[ac + 0][ar] = av.x; As[ac + 1][ar] = av.y;
        As[ac + 2][ar] = av.z; As[ac + 3][ar] = av.w;
        *(float4*)&Bs[bk][bn] = bv;
        __syncthreads();
#pragma unroll
        for (int k = 0; k < 16; ++k) {
            float4 a = *(const float4*)&As[k][rg * 4];
            float4 b = *(const float4*)&Bs[k][cg * 4];
            acc0.x = fmaf(a.x, b.x, acc0.x); acc0.y = fmaf(a.x, b.y, acc0.y);
            acc0.z = fmaf(a.x, b.z, acc0.z); acc0.w = fmaf(a.x, b.w, acc0.w);
            acc1.x = fmaf(a.y, b.x, acc1.x); acc1.y = fmaf(a.y, b.y, acc1.y);
            acc1.z = fmaf(a.y, b.z, acc1.z); acc1.w = fmaf(a.y, b.w, acc1.w);
            acc2.x = fmaf(a.z, b.x, acc2.x); acc2.y = fmaf(a.z, b.y, acc2.y);
            acc2.z = fmaf(a.z, b.z, acc2.z); acc2.w = fmaf(a.z, b.w, acc2.w);
            acc3.x = fmaf(a.w, b.x, acc3.x); acc3.y = fmaf(a.w, b.y, acc3.y);
            acc3.z = fmaf(a.w, b.z, acc3.z); acc3.w = fmaf(a.w, b.w, acc3.w);
        }
        __syncthreads();
    }

    int row = rowBase + rg * 4;
    int col = colBase + cg * 4;
    float4 bb = *(const float4*)(bias + col);

    ushort4 o;
    o.x = f2bf(acc0.x + bb.x); o.y = f2bf(acc0.y + bb.y);
    o.z = f2bf(acc0.z + bb.z); o.w = f2bf(acc0.w + bb.w);
    *(ushort4*)(C + (size_t)(row + 0) * HID + col) = o;
    o.x = f2bf(acc1.x + bb.x); o.y = f2bf(acc1.y + bb.y);
    o.z = f2bf(acc1.z + bb.z); o.w = f2bf(acc1.w + bb.w);
    *(ushort4*)(C + (size_t)(row + 1) * HID + col) = o;
    o.x = f2bf(acc2.x + bb.x); o.y = f2bf(acc2.y + bb.y);
    o.z = f2bf(acc2.z + bb.z); o.w = f2bf(acc2.w + bb.w);
    *(ushort4*)(C + (size_t)(row + 2) * HID + col) = o;
    o.x = f2bf(acc3.x + bb.x); o.y = f2bf(acc3.y + bb.y);
    o.z = f2bf(acc3.z + bb.z); o.w = f2bf(acc3.w + bb.w);
    *(ushort4*)(C + (size_t)(row + 3) * HID + col) = o;
}

// ---------------------------------------------------------------------------
// MFMA GEMM, A pure bf16: u16 = bf16((h @ W) * norm[row]).
// A exact bf16 -> only 2 MFMAs per tile: A*Bhi + A*Blo.  64x64, grid (250,4).
// ---------------------------------------------------------------------------
__global__ __launch_bounds__(256) void mfma_gemm_kernel(const unsigned short* __restrict__ A,
                                                        const unsigned short* __restrict__ WThi,
                                                        const unsigned short* __restrict__ WTlo,
                                                        unsigned short* __restrict__ C,
                                                        const float* __restrict__ rowscale) {
    __shared__ unsigned short Ah[64][40];
    __shared__ unsigned short Bh[64][40], Bl[64][40];
    int tid = threadIdx.x;
    int rowBase = blockIdx.x * 64;
    int colBase = blockIdx.y * 64;
    int wave = tid >> 6;
    int lane = tid & 63;
    int fr = lane & 15;
    int fg = lane >> 4;

    int asr = tid >> 2;          // 0..63 : row (A) / col (WT row)
    int ask = (tid & 3) * 8;     // k-offset, 8 ushorts = 16 B

    f4v acc[4];
#pragma unroll
    for (int c = 0; c < 4; ++c) acc[c] = (f4v){0.f, 0.f, 0.f, 0.f};

    for (int kb = 0; kb < HID; kb += 32) {
        uint4 av = *(const uint4*)(A    + (size_t)(rowBase + asr) * HID + kb + ask);
        uint4 bh = *(const uint4*)(WThi + (size_t)(colBase + asr) * HID + kb + ask);
        uint4 bl = *(const uint4*)(WTlo + (size_t)(colBase + asr) * HID + kb + ask);
        __syncthreads();
        *(uint4*)&Ah[asr][ask] = av;
        *(uint4*)&Bh[asr][ask] = bh;
        *(uint4*)&Bl[asr][ask] = bl;
        __syncthreads();

        s8v af = *(s8v*)&Ah[wave * 16 + fr][fg * 8];
#pragma unroll
        for (int c = 0; c < 4; ++c) {
            s8v bfh = *(s8v*)&Bh[c * 16 + fr][fg * 8];
            s8v bfl = *(s8v*)&Bl[c * 16 + fr][fg * 8];
            acc[c] = __builtin_amdgcn_mfma_f32_16x16x32_bf16(af, bfh, acc[c], 0, 0, 0);
            acc[c] = __builtin_amdgcn_mfma_f32_16x16x32_bf16(af, bfl, acc[c], 0, 0, 0);
        }
    }

    float sc[4];
#pragma unroll
    for (int r = 0; r < 4; ++r) sc[r] = rowscale[rowBase + wave * 16 + fg * 4 + r];
#pragma unroll
    for (int c = 0; c < 4; ++c) {
        int col = colBase + c * 16 + fr;
#pragma unroll
        for (int r = 0; r < 4; ++r) {
            int row = rowBase + wave * 16 + fg * 4 + r;
            C[(size_t)row * HID + col] = f2bf(acc[c][r] * sc[r]);
        }
    }
}

// ---------------------------------------------------------------------------
// Aggregation: h[j] = relu(norm[j]*(u[j]+sum_in u)+b), bf16 in/out.
// If gsumP != null (last layer): block partial feature sums -> gsumP.
// ---------------------------------------------------------------------------
__global__ __launch_bounds__(256) void agg_kernel(const unsigned short* __restrict__ u,
                                                  const float* __restrict__ norm,
                                                  const float* __restrict__ bias,
                                                  const int* __restrict__ offs,
                                                  const int* __restrict__ adj,
                                                  unsigned short* __restrict__ hout,
                                                  float* __restrict__ gsumP) {
    __shared__ float sacc[256];
    int tid  = threadIdx.x;
    int node = blockIdx.x * 4 + (tid >> 6);
    int lane = tid & 63;
    const ushort4* up = (const ushort4*)u;
    ushort4 sv = up[(size_t)node * 64 + lane];
    float ax = bf2f(sv.x), ay = bf2f(sv.y), az = bf2f(sv.z), aw = bf2f(sv.w);
    int e0 = offs[node], e1 = offs[node + 1];
    for (int e = e0; e < e1; ++e) {
        int s = adj[e];
        ushort4 v = up[(size_t)s * 64 + lane];
        ax += bf2f(v.x); ay += bf2f(v.y); az += bf2f(v.z); aw += bf2f(v.w);
    }
    float nm = norm[node];
    float4 bb = ((const float4*)bias)[lane];
    float4 r;
    r.x = fmaxf(fmaf(nm, ax, bb.x), 0.0f);
    r.y = fmaxf(fmaf(nm, ay, bb.y), 0.0f);
    r.z = fmaxf(fmaf(nm, az, bb.z), 0.0f);
    r.w = fmaxf(fmaf(nm, aw, bb.w), 0.0f);
    ushort4 o;
    o.x = f2bf(r.x); o.y = f2bf(r.y); o.z = f2bf(r.z); o.w = f2bf(r.w);
    ((ushort4*)hout)[(size_t)node * 64 + lane] = o;

    if (gsumP) {
        sacc[tid] = 0.0f;
        __syncthreads();
        atomicAdd(&sacc[lane * 4 + 0], r.x);
        atomicAdd(&sacc[lane * 4 + 1], r.y);
        atomicAdd(&sacc[lane * 4 + 2], r.z);
        atomicAdd(&sacc[lane * 4 + 3], r.w);
        __syncthreads();
        atomicAdd(&gsumP[(blockIdx.x & 63) * 256 + tid], sacc[tid]);
    }
}

// ---------------------------------------------------------------------------
// Head: reduce 64 pool partials, then 2-layer MLP (f32).
// ---------------------------------------------------------------------------
__global__ __launch_bounds__(128) void head_kernel(const float* __restrict__ gsumP,
                                                   const float* __restrict__ Wp1,
                                                   const float* __restrict__ bp1,
                                                   const float* __restrict__ Wp2,
                                                   const float* __restrict__ bp2,
                                                   float* __restrict__ out) {
    __shared__ float gl[256];
    __shared__ float hid[128];
    int t = threadIdx.x;
    const float inv = 1.0f / 16000.0f;
    float s0 = 0.f, s1 = 0.f;
    for (int p = 0; p < 64; ++p) {
        s0 += gsumP[p * 256 + t];
        s1 += gsumP[p * 256 + t + 128];
    }
    gl[t]       = s0 * inv;
    gl[t + 128] = s1 * inv;
    __syncthreads();
    float a = bp1[t];
    for (int k = 0; k < 256; ++k) a = fmaf(gl[k], Wp1[k * 128 + t], a);
    hid[t] = fmaxf(a, 0.0f);
    __syncthreads();
    float o = bp2[t];
    for (int k = 0; k < 128; ++k) o = fmaf(hid[k], Wp2[k * 128 + t], o);
    out[t] = o;
}

// ---------------------------------------------------------------------------
extern "C" void kernel_launch(void* const* d_in, const int* in_sizes, int n_in,
                              void* d_out, int out_size, void* d_ws, size_t ws_size,
                              hipStream_t stream) {
    const float* x      = (const float*)d_in[0];
    const float* coords = (const float*)d_in[1];
    const float* We     = (const float*)d_in[2];
    const float* be     = (const float*)d_in[3];
    const float* gnn_W  = (const float*)d_in[4];
    const float* gnn_b  = (const float*)d_in[5];
    const float* Wp1    = (const float*)d_in[6];
    const float* bp1    = (const float*)d_in[7];
    const float* Wp2    = (const float*)d_in[8];
    const float* bp2    = (const float*)d_in[9];
    float* out = (float*)d_out;

    char* ws = (char*)d_ws;
    // ws layout, high-water 34,311,424 B (proven).
    // NOTE: never end a comment with a backslash (line continuation!).
    unsigned short* h = (unsigned short*)(ws + 0);  // 8,192,000 B bf16
    char*  ureg  = ws + 16384000;             // 16,384,000 B multi-use region
    int*   nbr   = (int*)  (ws + 32768000);   // 512,000 B
    int*   adj   = (int*)  (ws + 33280000);   // 512,000 B
    int*   indeg = (int*)  (ws + 33792000);   // 64,000 B (zeroA start)
    int*   cursor= (int*)  (ws + 33856000);   // 64,000 B (zeroA end: 128,000 B)
    int*   offs  = (int*)  (ws + 33921024);   // 64,004 B
    float* norm  = (float*)(ws + 33985152);   // 64,000 B
    float4* cand = (float4*)(ws + 34049280);  // 262,144 B

    // ureg during kNN: minv, tau, cnt.  During GNN: u16, WThi, WTlo, gsumP.
    unsigned short* u16 = (unsigned short*)ureg;              // 8,192,000 B
    float*  minv = (float*)ureg;                              // 8,192,000 B
    float*  tau  = (float*)(ureg + 8192000);                  // 64,000 B
    int*    cnt  = (int*)  (ureg + 8256000);                  // 256,000 B
    unsigned short* WThi = (unsigned short*)(ureg + 8512000); // 393,216 B
    unsigned short* WTlo = (unsigned short*)(ureg + 8905216); // 393,216 B
    float*  gsumP = (float*)(ureg + 9298432);                 // 65,536 B (zeroB)
    float2* cl   = (float2*)(ws + 0);                         // 16,384,000 B (kNN phase)

    prep_kernel<<<NPAD / 256, 256, 0, stream>>>(coords, cand, (int4*)indeg, (int4*)gsumP);
    knn_min_kernel<<<dim3(N_NODES / 64, PARTS), 256, 0, stream>>>(coords, cand, minv);
    tau_kernel<<<(N_NODES + 255) / 256, 256, 0, stream>>>(minv, tau);
    knn_collect_kernel<<<dim3(N_NODES / 64, PARTS), 256, 0, stream>>>(coords, cand, tau, cnt, cl);
    knn_select_kernel<<<(N_NODES + 127) / 128, 128, 0, stream>>>(coords, cand, cl, cnt, nbr, indeg);

    scan_kernel<<<1, 1024, 0, stream>>>(indeg, offs, norm);
    fill_kernel<<<(NEDGE + 255) / 256, 256, 0, stream>>>(nbr, offs, cursor, adj);

    // encoder GEMM (y=0..3) + wsplit slice (y=4) in one dispatch
    gemm_kernel<<<dim3(N_NODES / 64, 5), 256, 0, stream>>>(x, We, h, F_IN, be,
                                                           gnn_W, WThi, WTlo);
    for (int l = 0; l < LAYERS; ++l) {
        mfma_gemm_kernel<<<dim3(N_NODES / 64, 4), 256, 0, stream>>>(
            h, WThi + (size_t)l * 65536, WTlo + (size_t)l * 65536, u16, norm);
        agg_kernel<<<N_NODES / 4, 256, 0, stream>>>(u16, norm, gnn_b + (size_t)l * HID,
                                                    offs, adj, h,
                                                    (l == LAYERS - 1) ? gsumP : nullptr);
    }
    head_kernel<<<1, 128, 0, stream>>>(gsumP, Wp1, bp1, Wp2, bp2, out);
}

// Round 13
// 264.350 us; speedup vs baseline: 1.1364x; 1.0429x over previous
//
#include <hip/hip_runtime.h>
#include <math.h>

#define N_NODES 16000
#define F_IN    16
#define HID     256
#define OUTD    128
#define KNN     8
#define LAYERS  3
#define NEDGE   (N_NODES * KNN)

#define NPAD    16384
#define PARTS   4
#define PART_SZ (NPAD / PARTS)   // 4096
#define SEGS    32               // segs per part (8 queries/thread)
#define NMIN    (PARTS * SEGS)   // 128 per-seg minima per query
#define CAPP    32               // collected-candidate cap per (query, part)

typedef __attribute__((ext_vector_type(8))) short  s8v;   // 8 bf16
typedef __attribute__((ext_vector_type(4))) float  f4v;

__device__ __forceinline__ unsigned short f2bf(float x) {
    unsigned u = __float_as_uint(x);
    unsigned r = u + 0x7fffu + ((u >> 16) & 1u);   // RNE
    return (unsigned short)(r >> 16);
}
__device__ __forceinline__ float bf2f(unsigned short b) {
    return __uint_as_float(((unsigned)b) << 16);
}

// ---------------------------------------------------------------------------
// cand[i] = (-2x, -2y, -2z, |c|^2); INF-padded. Shifted distance
// d' = fma(qx,-2x, fma(qy,-2y, fma(qz,-2z, |c|^2))) is per-query monotone.
// Also zeroes indeg+cursor (8000 int4) and gsumP (4096 int4).
// ---------------------------------------------------------------------------
__global__ __launch_bounds__(256) void prep_kernel(const float* __restrict__ coords,
                                                   float4* __restrict__ cand,
                                                   int4* __restrict__ zeroA,
                                                   int4* __restrict__ zeroB) {
    int i = blockIdx.x * 256 + threadIdx.x;
    int4 z4 = {0, 0, 0, 0};
    if (i < 8000) zeroA[i] = z4;
    if (i < 4096) zeroB[i] = z4;
    if (i >= NPAD) return;
    if (i < N_NODES) {
        float x = coords[3 * i], y = coords[3 * i + 1], z2 = coords[3 * i + 2];
        cand[i] = make_float4(-2.f * x, -2.f * y, -2.f * z2, x * x + y * y + z2 * z2);
    } else {
        cand[i] = make_float4(0.f, 0.f, 0.f, INFINITY);
    }
}

#define DIST(qx, qy, qz, c) fmaf(qx, c.x, fmaf(qy, c.y, fmaf(qz, c.z, c.w)))

// ---------------------------------------------------------------------------
// Phase 1: per (query, part, seg) minimum over the FULL part (tight tau is
// load-bearing: loose tau -> CAPP overflow -> serial fallback tail, round 11).
// 8 queries/thread, branchless, direct L2 reads (cand = 256 KB, L2-resident).
// ---------------------------------------------------------------------------
__global__ __launch_bounds__(256) void knn_min_kernel(const float* __restrict__ coords,
                                                      const float4* __restrict__ cand,
                                                      float* __restrict__ minv) {
    int tid  = threadIdx.x;
    int seg  = tid & 31;
    int qg   = tid >> 5;
    int qbase = blockIdx.x * 64;
    int part = blockIdx.y;

    float qx[8], qy[8], qz[8], m[8];
#pragma unroll
    for (int i = 0; i < 8; ++i) {
        int q = qbase + i * 8 + qg;
        qx[i] = coords[q * 3]; qy[i] = coords[q * 3 + 1]; qz[i] = coords[q * 3 + 2];
        m[i] = INFINITY;
    }

    int pbase = part * PART_SZ;
#pragma unroll 2
    for (int c0 = 0; c0 < PART_SZ; c0 += 128) {
        float4 v0 = cand[pbase + c0 + seg];
        float4 v1 = cand[pbase + c0 + seg + 32];
        float4 v2 = cand[pbase + c0 + seg + 64];
        float4 v3 = cand[pbase + c0 + seg + 96];
#pragma unroll
        for (int i = 0; i < 8; ++i) {
            float d0 = DIST(qx[i], qy[i], qz[i], v0);
            float d1 = DIST(qx[i], qy[i], qz[i], v1);
            float d2 = DIST(qx[i], qy[i], qz[i], v2);
            float d3 = DIST(qx[i], qy[i], qz[i], v3);
            m[i] = fminf(m[i], fminf(fminf(d0, d1), fminf(d2, d3)));
        }
    }
#pragma unroll
    for (int i = 0; i < 8; ++i) {
        int q = qbase + i * 8 + qg;
        minv[(q * PARTS + part) * SEGS + seg] = m[i];
    }
}

// ---------------------------------------------------------------------------
// Phase 2: tau[q] = 9th smallest of 16 merged-list minima (each list = 8
// consecutive segs -> 16 distinct candidates -> 9th smallest >= d9: valid).
// ---------------------------------------------------------------------------
__global__ __launch_bounds__(256) void tau_kernel(const float* __restrict__ minv,
                                                  float* __restrict__ tau) {
    int q = blockIdx.x * 256 + threadIdx.x;
    if (q >= N_NODES) return;
    float b[9];
#pragma unroll
    for (int p = 0; p < 9; ++p) b[p] = INFINITY;
    const float4* mv = (const float4*)(minv + (size_t)q * NMIN);
#pragma unroll
    for (int c = 0; c < 16; ++c) {
        float4 a0 = mv[c * 2], a1 = mv[c * 2 + 1];
        float v = fminf(fminf(fminf(a0.x, a0.y), fminf(a0.z, a0.w)),
                        fminf(fminf(a1.x, a1.y), fminf(a1.z, a1.w)));
#pragma unroll
        for (int p = 8; p >= 1; --p) {
            bool  up = v < b[p - 1];
            b[p] = up ? b[p - 1] : (v < b[p] ? v : b[p]);
        }
        if (v < b[0]) b[0] = v;
    }
    tau[q] = b[8];
}

// ---------------------------------------------------------------------------
// Phase 3: collect candidates with d <= tau[q]. min4-gate; direct L2 reads;
// block-local LDS counters. Identical fma as phase 1 -> bit-identical d.
// ---------------------------------------------------------------------------
__global__ __launch_bounds__(256) void knn_collect_kernel(const float* __restrict__ coords,
                                                          const float4* __restrict__ cand,
                                                          const float* __restrict__ tau,
                                                          int* __restrict__ cnt,
                                                          float2* __restrict__ cl) {
    __shared__ int scnt[64];
    int tid  = threadIdx.x;
    int seg  = tid & 31;
    int qg   = tid >> 5;
    int qbase = blockIdx.x * 64;
    int part  = blockIdx.y;

    float qx[8], qy[8], qz[8], tt[8];
#pragma unroll
    for (int i = 0; i < 8; ++i) {
        int q = qbase + i * 8 + qg;
        qx[i] = coords[q * 3]; qy[i] = coords[q * 3 + 1]; qz[i] = coords[q * 3 + 2];
        tt[i] = tau[q];
    }
    if (tid < 64) scnt[tid] = 0;
    __syncthreads();

    int pbase = part * PART_SZ;
#pragma unroll 2
    for (int c0 = 0; c0 < PART_SZ; c0 += 128) {
        float4 v0 = cand[pbase + c0 + seg];
        float4 v1 = cand[pbase + c0 + seg + 32];
        float4 v2 = cand[pbase + c0 + seg + 64];
        float4 v3 = cand[pbase + c0 + seg + 96];
        int jb = pbase + c0 + seg;
#pragma unroll
        for (int i = 0; i < 8; ++i) {
            float d0 = DIST(qx[i], qy[i], qz[i], v0);
            float d1 = DIST(qx[i], qy[i], qz[i], v1);
            float d2 = DIST(qx[i], qy[i], qz[i], v2);
            float d3 = DIST(qx[i], qy[i], qz[i], v3);
            float m4 = fminf(fminf(d0, d1), fminf(d2, d3));
            if (m4 <= tt[i]) {
                int qi = qbase + i * 8 + qg;
                int cb = (int)(((size_t)qi * PARTS + part) * CAPP);
                if (d0 <= tt[i]) {
                    int pos = atomicAdd(&scnt[i * 8 + qg], 1);
                    if (pos < CAPP) cl[cb + pos] = make_float2(d0, __int_as_float(jb));
                }
                if (d1 <= tt[i]) {
                    int pos = atomicAdd(&scnt[i * 8 + qg], 1);
                    if (pos < CAPP) cl[cb + pos] = make_float2(d1, __int_as_float(jb + 32));
                }
                if (d2 <= tt[i]) {
                    int pos = atomicAdd(&scnt[i * 8 + qg], 1);
                    if (pos < CAPP) cl[cb + pos] = make_float2(d2, __int_as_float(jb + 64));
                }
                if (d3 <= tt[i]) {
                    int pos = atomicAdd(&scnt[i * 8 + qg], 1);
                    if (pos < CAPP) cl[cb + pos] = make_float2(d3, __int_as_float(jb + 96));
                }
            }
        }
    }
    __syncthreads();
    if (tid < 64) cnt[(size_t)(qbase + tid) * PARTS + part] = scnt[tid];
}

// ---------------------------------------------------------------------------
// Phase 4: exact lexicographic (d, idx) top-9 over the 4 part segments.
// Also counts indegree (fused). Fallback exact rescan (~never fires with
// tight tau). 128-thread blocks for grid spread.
// ---------------------------------------------------------------------------
#define INS9L(bd, bi, d, j)                                                   \
    {                                                                         \
        _Pragma("unroll")                                                     \
        for (int p = 8; p >= 1; --p) {                                        \
            bool up = (d) < bd[p-1] || ((d) == bd[p-1] && (j) < bi[p-1]);     \
            bool in = (d) < bd[p]   || ((d) == bd[p]   && (j) < bi[p]);       \
            float nd = up ? bd[p-1] : (in ? (d) : bd[p]);                     \
            int   ni = up ? bi[p-1] : (in ? (j) : bi[p]);                     \
            bd[p] = nd; bi[p] = ni;                                           \
        }                                                                     \
        if ((d) < bd[0] || ((d) == bd[0] && (j) < bi[0])) {                   \
            bd[0] = (d); bi[0] = (j);                                         \
        }                                                                     \
    }

__global__ __launch_bounds__(128) void knn_select_kernel(const float* __restrict__ coords,
                                                         const float4* __restrict__ cand,
                                                         const float2* __restrict__ cl,
                                                         const int* __restrict__ cnt,
                                                         int* __restrict__ nbr,
                                                         int* __restrict__ indeg) {
    int q = blockIdx.x * 128 + threadIdx.x;
    if (q >= N_NODES) return;
    float bd[9]; int bi[9];
#pragma unroll
    for (int p = 0; p < 9; ++p) { bd[p] = INFINITY; bi[p] = 0x7fffffff; }
    int n0 = cnt[(size_t)q * PARTS + 0];
    int n1 = cnt[(size_t)q * PARTS + 1];
    int n2 = cnt[(size_t)q * PARTS + 2];
    int n3 = cnt[(size_t)q * PARTS + 3];
    if (n0 <= CAPP && n1 <= CAPP && n2 <= CAPP && n3 <= CAPP) {
#pragma unroll
        for (int p = 0; p < PARTS; ++p) {
            int n = (p == 0) ? n0 : (p == 1) ? n1 : (p == 2) ? n2 : n3;
            const float2* segp = cl + ((size_t)q * PARTS + p) * CAPP;
            for (int i = 0; i < n; ++i) {
                float2 e = segp[i];
                float d = e.x; int j = __float_as_int(e.y);
                INS9L(bd, bi, d, j);
            }
        }
    } else {
        float qx = coords[q*3], qy = coords[q*3+1], qz = coords[q*3+2];
        for (int j = 0; j < NPAD; ++j) {
            float4 c = cand[j];
            float d = DIST(qx, qy, qz, c);
            if (d < bd[8] || (d == bd[8] && j < bi[8])) INS9L(bd, bi, d, j);
        }
    }
#pragma unroll
    for (int p = 1; p < 9; ++p) {
        nbr[q * 8 + p - 1] = bi[p];
        atomicAdd(&indeg[bi[p]], 1);
    }
}

// ---------------------------------------------------------------------------
// CSR: exclusive scan (+norm) over indegree, then fill.
// ---------------------------------------------------------------------------
__global__ __launch_bounds__(1024) void scan_kernel(const int* __restrict__ indeg,
                                                    int* __restrict__ offs,
                                                    float* __restrict__ norm) {
    __shared__ int ssum[1024];
    int t = threadIdx.x;
    const int CH = 16;
    int base = t * CH;
    int s = 0;
    for (int c = 0; c < CH; ++c) {
        int idx = base + c;
        if (idx < N_NODES) s += indeg[idx];
    }
    ssum[t] = s;
    __syncthreads();
    for (int d = 1; d < 1024; d <<= 1) {
        int v = (t >= d) ? ssum[t - d] : 0;
        __syncthreads();
        ssum[t] += v;
        __syncthreads();
    }
    int run = ssum[t] - s;
    for (int c = 0; c < CH; ++c) {
        int idx = base + c;
        if (idx < N_NODES) {
            int dg = indeg[idx];
            offs[idx] = run;
            run += dg;
            norm[idx] = rsqrtf((float)(1 + dg));
        }
    }
    if (t == 1023) offs[N_NODES] = ssum[1023];
}

__global__ void fill_kernel(const int* __restrict__ nbr, const int* __restrict__ offs,
                            int* __restrict__ cursor, int* __restrict__ adj) {
    int e = blockIdx.x * blockDim.x + threadIdx.x;
    if (e < NEDGE) {
        int d   = nbr[e];
        int src = e >> 3;
        int pos = atomicAdd(&cursor[d], 1);
        adj[offs[d] + pos] = src;
    }
}

// ---------------------------------------------------------------------------
// Encoder GEMM (f32 in, bf16 out, K=16): h = bf16(x @ We + be).
// blockIdx.y==4 slice performs the W transpose+split (barrier-free branch).
// ---------------------------------------------------------------------------
__global__ __launch_bounds__(256) void gemm_kernel(const float* __restrict__ A,
                                                   const float* __restrict__ B,
                                                   unsigned short* __restrict__ C,
                                                   int K,
                                                   const float* __restrict__ bias,
                                                   const float* __restrict__ Wg,
                                                   unsigned short* __restrict__ WThi,
                                                   unsigned short* __restrict__ WTlo) {
    if (blockIdx.y == 4) {
        for (int idx = blockIdx.x * 256 + threadIdx.x; idx < LAYERS * 65536;
             idx += 64000) {
            int l = idx >> 16;
            int r = idx & 65535;
            int k = r >> 8, j = r & 255;
            float xv = Wg[idx];
            unsigned short hb = f2bf(xv);
            size_t o = (size_t)l * 65536 + j * 256 + k;
            WThi[o] = hb;
            WTlo[o] = f2bf(xv - bf2f(hb));
        }
        return;
    }
    __shared__ float As[16][68];
    __shared__ float Bs[16][64];
    int tid = threadIdx.x;
    int rowBase = blockIdx.x * 64;
    int colBase = blockIdx.y * 64;
    int rg = tid >> 4;
    int cg = tid & 15;

    int ar = tid >> 2;
    int ac = (tid & 3) * 4;
    int bk = tid >> 4;
    int bn = (tid & 15) * 4;

    float4 acc0 = {0,0,0,0}, acc1 = {0,0,0,0}, acc2 = {0,0,0,0}, acc3 = {0,0,0,0};

    for (int kb = 0; kb < K; kb += 16) {
        float4 av = *(const float4*)(A + (size_t)(rowBase + ar) * K + kb + ac);
        float4 bv = *(const float4*)(B + (size_t)(kb + bk) * HID + colBase + bn);
        __syncthreads();
        As[ac + 0][ar] = av.x; As[ac + 1][ar] = av.y;
        As[ac + 2][ar] = av.z; As[ac + 3][ar] = av.w;
        *(float4*)&Bs[bk][bn] = bv;
        __syncthreads();
#pragma unroll
        for (int k = 0; k < 16; ++k) {
            float4 a = *(const float4*)&As[k][rg * 4];
            float4 b = *(const float4*)&Bs[k][cg * 4];
            acc0.x = fmaf(a.x, b.x, acc0.x); acc0.y = fmaf(a.x, b.y, acc0.y);
            acc0.z = fmaf(a.x, b.z, acc0.z); acc0.w = fmaf(a.x, b.w, acc0.w);
            acc1.x = fmaf(a.y, b.x, acc1.x); acc1.y = fmaf(a.y, b.y, acc1.y);
            acc1.z = fmaf(a.y, b.z, acc1.z); acc1.w = fmaf(a.y, b.w, acc1.w);
            acc2.x = fmaf(a.z, b.x, acc2.x); acc2.y = fmaf(a.z, b.y, acc2.y);
            acc2.z = fmaf(a.z, b.z, acc2.z); acc2.w = fmaf(a.z, b.w, acc2.w);
            acc3.x = fmaf(a.w, b.x, acc3.x); acc3.y = fmaf(a.w, b.y, acc3.y);
            acc3.z = fmaf(a.w, b.z, acc3.z); acc3.w = fmaf(a.w, b.w, acc3.w);
        }
        __syncthreads();
    }

    int row = rowBase + rg * 4;
    int col = colBase + cg * 4;
    float4 bb = *(const float4*)(bias + col);

    ushort4 o;
    o.x = f2bf(acc0.x + bb.x); o.y = f2bf(acc0.y + bb.y);
    o.z = f2bf(acc0.z + bb.z); o.w = f2bf(acc0.w + bb.w);
    *(ushort4*)(C + (size_t)(row + 0) * HID + col) = o;
    o.x = f2bf(acc1.x + bb.x); o.y = f2bf(acc1.y + bb.y);
    o.z = f2bf(acc1.z + bb.z); o.w = f2bf(acc1.w + bb.w);
    *(ushort4*)(C + (size_t)(row + 1) * HID + col) = o;
    o.x = f2bf(acc2.x + bb.x); o.y = f2bf(acc2.y + bb.y);
    o.z = f2bf(acc2.z + bb.z); o.w = f2bf(acc2.w + bb.w);
    *(ushort4*)(C + (size_t)(row + 2) * HID + col) = o;
    o.x = f2bf(acc3.x + bb.x); o.y = f2bf(acc3.y + bb.y);
    o.z = f2bf(acc3.z + bb.z); o.w = f2bf(acc3.w + bb.w);
    *(ushort4*)(C + (size_t)(row + 3) * HID + col) = o;
}

// ---------------------------------------------------------------------------
// MFMA GEMM, A pure bf16: u16 = bf16((h @ W) * norm[row]).
// A exact bf16 -> only 2 MFMAs per tile: A*Bhi + A*Blo.  64x64, grid (250,4).
// ---------------------------------------------------------------------------
__global__ __launch_bounds__(256) void mfma_gemm_kernel(const unsigned short* __restrict__ A,
                                                        const unsigned short* __restrict__ WThi,
                                                        const unsigned short* __restrict__ WTlo,
                                                        unsigned short* __restrict__ C,
                                                        const float* __restrict__ rowscale) {
    __shared__ unsigned short Ah[64][40];
    __shared__ unsigned short Bh[64][40], Bl[64][40];
    int tid = threadIdx.x;
    int rowBase = blockIdx.x * 64;
    int colBase = blockIdx.y * 64;
    int wave = tid >> 6;
    int lane = tid & 63;
    int fr = lane & 15;
    int fg = lane >> 4;

    int asr = tid >> 2;          // 0..63 : row (A) / col (WT row)
    int ask = (tid & 3) * 8;     // k-offset, 8 ushorts = 16 B

    f4v acc[4];
#pragma unroll
    for (int c = 0; c < 4; ++c) acc[c] = (f4v){0.f, 0.f, 0.f, 0.f};

    for (int kb = 0; kb < HID; kb += 32) {
        uint4 av = *(const uint4*)(A    + (size_t)(rowBase + asr) * HID + kb + ask);
        uint4 bh = *(const uint4*)(WThi + (size_t)(colBase + asr) * HID + kb + ask);
        uint4 bl = *(const uint4*)(WTlo + (size_t)(colBase + asr) * HID + kb + ask);
        __syncthreads();
        *(uint4*)&Ah[asr][ask] = av;
        *(uint4*)&Bh[asr][ask] = bh;
        *(uint4*)&Bl[asr][ask] = bl;
        __syncthreads();

        s8v af = *(s8v*)&Ah[wave * 16 + fr][fg * 8];
#pragma unroll
        for (int c = 0; c < 4; ++c) {
            s8v bfh = *(s8v*)&Bh[c * 16 + fr][fg * 8];
            s8v bfl = *(s8v*)&Bl[c * 16 + fr][fg * 8];
            acc[c] = __builtin_amdgcn_mfma_f32_16x16x32_bf16(af, bfh, acc[c], 0, 0, 0);
            acc[c] = __builtin_amdgcn_mfma_f32_16x16x32_bf16(af, bfl, acc[c], 0, 0, 0);
        }
    }

    float sc[4];
#pragma unroll
    for (int r = 0; r < 4; ++r) sc[r] = rowscale[rowBase + wave * 16 + fg * 4 + r];
#pragma unroll
    for (int c = 0; c < 4; ++c) {
        int col = colBase + c * 16 + fr;
#pragma unroll
        for (int r = 0; r < 4; ++r) {
            int row = rowBase + wave * 16 + fg * 4 + r;
            C[(size_t)row * HID + col] = f2bf(acc[c][r] * sc[r]);
        }
    }
}

// ---------------------------------------------------------------------------
// Aggregation: h[j] = relu(norm[j]*(u[j]+sum_in u)+b), bf16 in/out.
// TWO nodes per wave -> 2 independent gather chains in flight (2x MLP).
// If gsumP != null (last layer): block partial feature sums -> gsumP.
// ---------------------------------------------------------------------------
__global__ __launch_bounds__(256) void agg_kernel(const unsigned short* __restrict__ u,
                                                  const float* __restrict__ norm,
                                                  const float* __restrict__ bias,
                                                  const int* __restrict__ offs,
                                                  const int* __restrict__ adj,
                                                  unsigned short* __restrict__ hout,
                                                  float* __restrict__ gsumP) {
    __shared__ float sacc[256];
    int tid  = threadIdx.x;
    int w    = tid >> 6;
    int lane = tid & 63;
    int n0 = blockIdx.x * 8 + w;
    int n1 = n0 + 4;
    const ushort4* up = (const ushort4*)u;

    ushort4 s0 = up[(size_t)n0 * 64 + lane];
    ushort4 s1 = up[(size_t)n1 * 64 + lane];
    float a0x = bf2f(s0.x), a0y = bf2f(s0.y), a0z = bf2f(s0.z), a0w = bf2f(s0.w);
    float a1x = bf2f(s1.x), a1y = bf2f(s1.y), a1z = bf2f(s1.z), a1w = bf2f(s1.w);

    int ea = offs[n0], e1a = offs[n0 + 1];
    int eb = offs[n1], e1b = offs[n1 + 1];
    while (ea < e1a || eb < e1b) {          // wave-uniform loop
        bool va = ea < e1a, vb = eb < e1b;
        int sa = va ? adj[ea] : 0;
        int sb = vb ? adj[eb] : 0;
        ushort4 uva = up[(size_t)sa * 64 + lane];   // 2 independent gathers
        ushort4 uvb = up[(size_t)sb * 64 + lane];
        if (va) { a0x += bf2f(uva.x); a0y += bf2f(uva.y);
                  a0z += bf2f(uva.z); a0w += bf2f(uva.w); }
        if (vb) { a1x += bf2f(uvb.x); a1y += bf2f(uvb.y);
                  a1z += bf2f(uvb.z); a1w += bf2f(uvb.w); }
        ea += va; eb += vb;
    }

    float nm0 = norm[n0], nm1 = norm[n1];
    float4 bb = ((const float4*)bias)[lane];
    float4 r0, r1;
    r0.x = fmaxf(fmaf(nm0, a0x, bb.x), 0.0f);
    r0.y = fmaxf(fmaf(nm0, a0y, bb.y), 0.0f);
    r0.z = fmaxf(fmaf(nm0, a0z, bb.z), 0.0f);
    r0.w = fmaxf(fmaf(nm0, a0w, bb.w), 0.0f);
    r1.x = fmaxf(fmaf(nm1, a1x, bb.x), 0.0f);
    r1.y = fmaxf(fmaf(nm1, a1y, bb.y), 0.0f);
    r1.z = fmaxf(fmaf(nm1, a1z, bb.z), 0.0f);
    r1.w = fmaxf(fmaf(nm1, a1w, bb.w), 0.0f);
    ushort4 o0, o1;
    o0.x = f2bf(r0.x); o0.y = f2bf(r0.y); o0.z = f2bf(r0.z); o0.w = f2bf(r0.w);
    o1.x = f2bf(r1.x); o1.y = f2bf(r1.y); o1.z = f2bf(r1.z); o1.w = f2bf(r1.w);
    ((ushort4*)hout)[(size_t)n0 * 64 + lane] = o0;
    ((ushort4*)hout)[(size_t)n1 * 64 + lane] = o1;

    if (gsumP) {
        sacc[tid] = 0.0f;
        __syncthreads();
        atomicAdd(&sacc[lane * 4 + 0], r0.x + r1.x);
        atomicAdd(&sacc[lane * 4 + 1], r0.y + r1.y);
        atomicAdd(&sacc[lane * 4 + 2], r0.z + r1.z);
        atomicAdd(&sacc[lane * 4 + 3], r0.w + r1.w);
        __syncthreads();
        atomicAdd(&gsumP[(blockIdx.x & 63) * 256 + tid], sacc[tid]);
    }
}

// ---------------------------------------------------------------------------
// Head: reduce 64 pool partials, then 2-layer MLP (f32).
// ---------------------------------------------------------------------------
__global__ __launch_bounds__(128) void head_kernel(const float* __restrict__ gsumP,
                                                   const float* __restrict__ Wp1,
                                                   const float* __restrict__ bp1,
                                                   const float* __restrict__ Wp2,
                                                   const float* __restrict__ bp2,
                                                   float* __restrict__ out) {
    __shared__ float gl[256];
    __shared__ float hid[128];
    int t = threadIdx.x;
    const float inv = 1.0f / 16000.0f;
    float s0 = 0.f, s1 = 0.f;
    for (int p = 0; p < 64; ++p) {
        s0 += gsumP[p * 256 + t];
        s1 += gsumP[p * 256 + t + 128];
    }
    gl[t]       = s0 * inv;
    gl[t + 128] = s1 * inv;
    __syncthreads();
    float a = bp1[t];
    for (int k = 0; k < 256; ++k) a = fmaf(gl[k], Wp1[k * 128 + t], a);
    hid[t] = fmaxf(a, 0.0f);
    __syncthreads();
    float o = bp2[t];
    for (int k = 0; k < 128; ++k) o = fmaf(hid[k], Wp2[k * 128 + t], o);
    out[t] = o;
}

// ---------------------------------------------------------------------------
extern "C" void kernel_launch(void* const* d_in, const int* in_sizes, int n_in,
                              void* d_out, int out_size, void* d_ws, size_t ws_size,
                              hipStream_t stream) {
    const float* x      = (const float*)d_in[0];
    const float* coords = (const float*)d_in[1];
    const float* We     = (const float*)d_in[2];
    const float* be     = (const float*)d_in[3];
    const float* gnn_W  = (const float*)d_in[4];
    const float* gnn_b  = (const float*)d_in[5];
    const float* Wp1    = (const float*)d_in[6];
    const float* bp1    = (const float*)d_in[7];
    const float* Wp2    = (const float*)d_in[8];
    const float* bp2    = (const float*)d_in[9];
    float* out = (float*)d_out;

    char* ws = (char*)d_ws;
    // ws layout, high-water 34,311,424 B (proven).
    // NOTE: never end a comment with a backslash (line continuation!).
    unsigned short* h = (unsigned short*)(ws + 0);  // 8,192,000 B bf16
    char*  ureg  = ws + 16384000;             // 16,384,000 B multi-use region
    int*   nbr   = (int*)  (ws + 32768000);   // 512,000 B
    int*   adj   = (int*)  (ws + 33280000);   // 512,000 B
    int*   indeg = (int*)  (ws + 33792000);   // 64,000 B (zeroA start)
    int*   cursor= (int*)  (ws + 33856000);   // 64,000 B (zeroA end: 128,000 B)
    int*   offs  = (int*)  (ws + 33921024);   // 64,004 B
    float* norm  = (float*)(ws + 33985152);   // 64,000 B
    float4* cand = (float4*)(ws + 34049280);  // 262,144 B

    // ureg during kNN: minv, tau, cnt.  During GNN: u16, WThi, WTlo, gsumP.
    unsigned short* u16 = (unsigned short*)ureg;              // 8,192,000 B
    float*  minv = (float*)ureg;                              // 8,192,000 B
    float*  tau  = (float*)(ureg + 8192000);                  // 64,000 B
    int*    cnt  = (int*)  (ureg + 8256000);                  // 256,000 B
    unsigned short* WThi = (unsigned short*)(ureg + 8512000); // 393,216 B
    unsigned short* WTlo = (unsigned short*)(ureg + 8905216); // 393,216 B
    float*  gsumP = (float*)(ureg + 9298432);                 // 65,536 B (zeroB)
    float2* cl   = (float2*)(ws + 0);                         // 16,384,000 B (kNN phase)

    prep_kernel<<<NPAD / 256, 256, 0, stream>>>(coords, cand, (int4*)indeg, (int4*)gsumP);
    knn_min_kernel<<<dim3(N_NODES / 64, PARTS), 256, 0, stream>>>(coords, cand, minv);
    tau_kernel<<<(N_NODES + 255) / 256, 256, 0, stream>>>(minv, tau);
    knn_collect_kernel<<<dim3(N_NODES / 64, PARTS), 256, 0, stream>>>(coords, cand, tau, cnt, cl);
    knn_select_kernel<<<(N_NODES + 127) / 128, 128, 0, stream>>>(coords, cand, cl, cnt, nbr, indeg);

    scan_kernel<<<1, 1024, 0, stream>>>(indeg, offs, norm);
    fill_kernel<<<(NEDGE + 255) / 256, 256, 0, stream>>>(nbr, offs, cursor, adj);

    // encoder GEMM (y=0..3) + wsplit slice (y=4) in one dispatch
    gemm_kernel<<<dim3(N_NODES / 64, 5), 256, 0, stream>>>(x, We, h, F_IN, be,
                                                           gnn_W, WThi, WTlo);
    for (int l = 0; l < LAYERS; ++l) {
        mfma_gemm_kernel<<<dim3(N_NODES / 64, 4), 256, 0, stream>>>(
            h, WThi + (size_t)l * 65536, WTlo + (size_t)l * 65536, u16, norm);
        agg_kernel<<<N_NODES / 8, 256, 0, stream>>>(u16, norm, gnn_b + (size_t)l * HID,
                                                    offs, adj, h,
                                                    (l == LAYERS - 1) ? gsumP : nullptr);
    }
    head_kernel<<<1, 128, 0, stream>>>(gsumP, Wp1, bp1, Wp2, bp2, out);
}